// Round 5
// baseline (57.589 us; speedup 1.0000x reference)
//
#include <hip/hip_runtime.h>
#include <hip/hip_bf16.h>

#define M 256
#define NOUT 1024
#define KTOT 16384
#define RANK 16
#define NKC 32          // split-K factor (grid.z)
#define KCHUNK 512      // K per block = KTOT/NKC
#define BKC 64          // K per LDS stage (one chunk)
#define BM 128          // rows per block (2 row-tiles)
#define BN 128          // cols per block (8 col-tiles); wave tile 64x64

typedef __attribute__((ext_vector_type(8))) short bf16x8_t;
typedef __attribute__((ext_vector_type(4))) float f32x4_t;
typedef __attribute__((ext_vector_type(8))) unsigned short u16x8_t;

static __device__ __forceinline__ unsigned short f2bf(float f) {
  unsigned u = __builtin_bit_cast(unsigned, f);
  u += 0x7FFFu + ((u >> 16) & 1u);   // round-to-nearest-even
  return (unsigned short)(u >> 16);
}
static __device__ __forceinline__ float bf2f(unsigned short h) {
  unsigned u = ((unsigned)h) << 16;
  return __builtin_bit_cast(float, u);
}
static __device__ __forceinline__ bf16x8_t cvt8(float4 a, float4 b) {
  bf16x8_t r;
  r[0] = (short)f2bf(a.x); r[1] = (short)f2bf(a.y);
  r[2] = (short)f2bf(a.z); r[3] = (short)f2bf(a.w);
  r[4] = (short)f2bf(b.x); r[5] = (short)f2bf(b.y);
  r[6] = (short)f2bf(b.z); r[7] = (short)f2bf(b.w);
  return r;
}

// X stored chunk-blocked + bank-swizzled:
//   element (b, k):  chunk = k>>6, u = (k&63)>>3, el = k&7
//   pos = (chunk*256 + b)*64 + ((u ^ (b&7)) * 8) + el        (bf16)
// Linear global_load_lds of a chunk row-slice yields LDS rows of 128 B whose
// 16B slots are XOR-swizzled by (row&7) -> conflict-free ds_read_b128 frags.
__global__ __launch_bounds__(256) void build_x_kernel(
    const float* __restrict__ input, const float* __restrict__ coef,
    unsigned short* __restrict__ X)
{
  int idx = blockIdx.x * 256 + threadIdx.x;   // idx = b*1024 + i
  int b = idx >> 10, i = idx & 1023;
  float in = input[idx];
  const float* c = coef + b * RANK;
  u16x8_t lo, hi;
  #pragma unroll
  for (int r = 0; r < 8; ++r) lo[r] = f2bf(in * c[r]);
  #pragma unroll
  for (int r = 0; r < 8; ++r) hi[r] = f2bf(in * c[8 + r]);
  int chunk = i >> 2;            // (i*16) >> 6
  int u0 = (i & 3) * 2;          // first 16B slot index within the row
  size_t base = ((size_t)chunk * 256 + b) * 64;
  *(u16x8_t*)(X + base + (size_t)((u0    ) ^ (b & 7)) * 8) = lo;
  *(u16x8_t*)(X + base + (size_t)((u0 + 1) ^ (b & 7)) * 8) = hi;
}

// GEMM: part[kc][b][o] (bf16) = sum_{k in chunk kc} X[b][k] * W[o][k]
// Block 128x128, 4 waves in 2x2 grid, wave tile 64x64 (fm=4, fn=4) -> each
// A fragment read from LDS feeds 4 MFMAs (LDS-read pipe 4x lighter than BN=64).
// W loads go DIRECTLY global->reg in MFMA B-fragment layout (16 float4 per
// chunk, two named ping-pong sets P/Q -> one full region of latency cover),
// converted fp32->bf16 at use. X staged via global_load_lds into a TRIPLE
// buffer: STAGE(c+2) issued at region start has 2 full regions to land.
// SYNC keeps exactly this region's 20 loads in flight (never drains).
__global__ __launch_bounds__(256, 2) void gemm_kernel(
    const unsigned short* __restrict__ X, const float* __restrict__ W,
    unsigned short* __restrict__ part)
{
  __shared__ unsigned short As0[128 * 64];   // 16 KB
  __shared__ unsigned short As1[128 * 64];   // 16 KB
  __shared__ unsigned short As2[128 * 64];   // 16 KB

  const int tid = threadIdx.x;
  const int wid = tid >> 6, lane = tid & 63;
  const int lr = lane & 15, lg = lane >> 4;
  const int wr = wid >> 1, wc = wid & 1;       // 2x2 wave grid
  const int o0 = blockIdx.x * BN;              // col base
  const int m0 = blockIdx.y * BM;              // row base
  const int kc = blockIdx.z;
  const int ch0 = kc * (KCHUNK / BKC);         // global 64-k chunk base
  const int kb0 = kc * KCHUNK;

  f32x4_t acc[4][4];                           // [fm][fn]
  #pragma unroll
  for (int a = 0; a < 4; ++a)
    #pragma unroll
    for (int q = 0; q < 4; ++q) acc[a][q] = (f32x4_t)(0.0f);

  // W row pointers for the 4 fn-fragments: col = o0 + wc*64 + f*16 + lr
  const float* w0 = W + (size_t)(o0 + wc * 64 + lr) * KTOT + lg * 8;
  const float* w1 = w0 + (size_t)16 * KTOT;
  const float* w2 = w0 + (size_t)32 * KTOT;
  const float* w3 = w0 + (size_t)48 * KTOT;

  // raw W prefetch sets: {P,Q}{f}{it}{half}
  float4 P000, P001, P010, P011, P100, P101, P110, P111,
         P200, P201, P210, P211, P300, P301, P310, P311;
  float4 Q000, Q001, Q010, Q011, Q100, Q101, Q110, Q111,
         Q200, Q201, Q210, Q211, Q300, Q301, Q310, Q311;

  #define SB __builtin_amdgcn_sched_barrier(0);

  #define STAGE(cch, BUF)                                                    \
    {                                                                        \
      const unsigned short* srcb =                                           \
          X + ((size_t)(ch0 + (cch)) * 256 + m0) * 64;                       \
      _Pragma("unroll")                                                      \
      for (int j = 0; j < 4; ++j) {                                          \
        __builtin_amdgcn_global_load_lds(                                    \
            (const __attribute__((address_space(1))) unsigned int*)          \
                (srcb + (size_t)(j * 256 + tid) * 8),                        \
            (__attribute__((address_space(3))) unsigned int*)                \
                (&BUF[(j * 256 + tid) * 8]),                                 \
            16, 0, 0);                                                       \
      }                                                                      \
    }

  #define LOADB(S, cch)                                                      \
    {                                                                        \
      int ko = kb0 + (cch) * BKC;                                            \
      S##000 = *(const float4*)(w0 + ko);      S##001 = *(const float4*)(w0 + ko + 4);  \
      S##100 = *(const float4*)(w1 + ko);      S##101 = *(const float4*)(w1 + ko + 4);  \
      S##200 = *(const float4*)(w2 + ko);      S##201 = *(const float4*)(w2 + ko + 4);  \
      S##300 = *(const float4*)(w3 + ko);      S##301 = *(const float4*)(w3 + ko + 4);  \
      S##010 = *(const float4*)(w0 + ko + 32); S##011 = *(const float4*)(w0 + ko + 36); \
      S##110 = *(const float4*)(w1 + ko + 32); S##111 = *(const float4*)(w1 + ko + 36); \
      S##210 = *(const float4*)(w2 + ko + 32); S##211 = *(const float4*)(w2 + ko + 36); \
      S##310 = *(const float4*)(w3 + ko + 32); S##311 = *(const float4*)(w3 + ko + 36); \
    }

  #define COMPIT(S, IT, BUF)                                                 \
    {                                                                        \
      bf16x8_t b0 = cvt8(S##0##IT##0, S##0##IT##1);                          \
      bf16x8_t b1 = cvt8(S##1##IT##0, S##1##IT##1);                          \
      bf16x8_t b2 = cvt8(S##2##IT##0, S##2##IT##1);                          \
      bf16x8_t b3 = cvt8(S##3##IT##0, S##3##IT##1);                          \
      __builtin_amdgcn_s_setprio(1);                                         \
      _Pragma("unroll")                                                      \
      for (int fm = 0; fm < 4; ++fm) {                                       \
        int rl = wr * 64 + fm * 16 + lr;                                     \
        int slot = ((IT) * 4 + lg) ^ (lr & 7);                               \
        bf16x8_t av = *(const bf16x8_t*)&BUF[rl * 64 + slot * 8];            \
        acc[fm][0] = __builtin_amdgcn_mfma_f32_16x16x32_bf16(av, b0, acc[fm][0], 0, 0, 0); \
        acc[fm][1] = __builtin_amdgcn_mfma_f32_16x16x32_bf16(av, b1, acc[fm][1], 0, 0, 0); \
        acc[fm][2] = __builtin_amdgcn_mfma_f32_16x16x32_bf16(av, b2, acc[fm][2], 0, 0, 0); \
        acc[fm][3] = __builtin_amdgcn_mfma_f32_16x16x32_bf16(av, b3, acc[fm][3], 0, 0, 0); \
      }                                                                      \
      __builtin_amdgcn_s_setprio(0);                                         \
    }

  #define COMPUTE(S, BUF) COMPIT(S, 0, BUF) COMPIT(S, 1, BUF)

  // keep this region's 20 loads (STAGE 4 + LOADB 16) in flight; everything
  // older (incl. STAGE(c+1), issued last region) is guaranteed retired.
  #define SYNC(N)                                                            \
    asm volatile("s_waitcnt vmcnt(" #N ") lgkmcnt(0)" ::: "memory"); SB      \
    __builtin_amdgcn_s_barrier(); SB

  // ---- prologue: stage chunks 0,1; prefetch W chunk 0; wait own stages ----
  STAGE(0, As0) SB
  STAGE(1, As1) SB
  LOADB(P, 0) SB
  SYNC(16)

  // ---- straight-line regions; chunk c: buf c%3, raw set P(even)/Q(odd) ----
  STAGE(2, As2) SB LOADB(Q, 1) SB COMPUTE(P, As0) SYNC(20)
  STAGE(3, As0) SB LOADB(P, 2) SB COMPUTE(Q, As1) SYNC(20)
  STAGE(4, As1) SB LOADB(Q, 3) SB COMPUTE(P, As2) SYNC(20)
  STAGE(5, As2) SB LOADB(P, 4) SB COMPUTE(Q, As0) SYNC(20)
  STAGE(6, As0) SB LOADB(Q, 5) SB COMPUTE(P, As1) SYNC(20)
  STAGE(7, As1) SB LOADB(P, 6) SB COMPUTE(Q, As2) SYNC(20)
                   LOADB(Q, 7) SB COMPUTE(P, As0) SYNC(16)
                                  COMPUTE(Q, As1)

  // ---- epilogue: C/D layout col=lane&15, row=(lane>>4)*4+j ----
  unsigned short* p = part + (size_t)kc * (M * NOUT);
  #pragma unroll
  for (int fm = 0; fm < 4; ++fm) {
    #pragma unroll
    for (int f = 0; f < 4; ++f) {
      #pragma unroll
      for (int j = 0; j < 4; ++j) {
        int row = m0 + wr * 64 + fm * 16 + lg * 4 + j;
        int col = o0 + wc * 64 + f * 16 + lr;
        p[(size_t)row * NOUT + col] = f2bf(acc[fm][f][j]);
      }
    }
  }
  #undef STAGE
  #undef LOADB
  #undef COMPIT
  #undef COMPUTE
  #undef SYNC
  #undef SB
}

// out[b][o] = sum_kc bf2f(part[kc][b][o]) + sum_r bias[o][r]*coef[b][r]
__global__ __launch_bounds__(256) void reduce_bias_kernel(
    const unsigned short* __restrict__ part, const float* __restrict__ bias,
    const float* __restrict__ coef, float* __restrict__ out)
{
  int t = blockIdx.x * 256 + threadIdx.x;
  int idx8 = t * 8;                       // 8 consecutive outputs, same b
  int b = idx8 >> 10, o = idx8 & 1023;

  float s[8];
  #pragma unroll
  for (int j = 0; j < 8; ++j) s[j] = 0.f;

  #pragma unroll
  for (int c = 0; c < NKC; ++c) {
    u16x8_t v = *(const u16x8_t*)(part + (size_t)c * (M * NOUT) + idx8);
    #pragma unroll
    for (int j = 0; j < 8; ++j) s[j] += bf2f(v[j]);
  }

  const f32x4_t* cr = (const f32x4_t*)(coef + (size_t)b * RANK);
  f32x4_t c0 = cr[0], c1 = cr[1], c2 = cr[2], c3 = cr[3];
  #pragma unroll
  for (int j = 0; j < 8; ++j) {
    const f32x4_t* br = (const f32x4_t*)(bias + (size_t)(o + j) * RANK);
    f32x4_t b0 = br[0], b1 = br[1], b2 = br[2], b3 = br[3];
    float bb = 0.f;
    #pragma unroll
    for (int e = 0; e < 4; ++e)
      bb += b0[e] * c0[e] + b1[e] * c1[e] + b2[e] * c2[e] + b3[e] * c3[e];
    s[j] += bb;
  }
  float4* dst = (float4*)(out + idx8);
  dst[0] = make_float4(s[0], s[1], s[2], s[3]);
  dst[1] = make_float4(s[4], s[5], s[6], s[7]);
}

extern "C" void kernel_launch(void* const* d_in, const int* in_sizes, int n_in,
                              void* d_out, int out_size, void* d_ws, size_t ws_size,
                              hipStream_t stream) {
  const float* input = (const float*)d_in[0];   // (256, 1024)
  const float* coef  = (const float*)d_in[1];   // (256, 16)
  const float* W     = (const float*)d_in[2];   // (1024, 1024, 16) -> (1024, 16384)
  const float* bias  = (const float*)d_in[3];   // (1024, 16)
  float* out = (float*)d_out;                   // (256, 1024)

  unsigned short* X    = (unsigned short*)d_ws;                               // 8 MiB bf16
  unsigned short* part = (unsigned short*)((char*)d_ws + (size_t)M * KTOT * 2); // 16 MiB bf16

  build_x_kernel<<<(M * 1024) / 256, 256, 0, stream>>>(input, coef, X);
  gemm_kernel<<<dim3(NOUT / BN, M / BM, NKC), 256, 0, stream>>>(X, W, part);
  reduce_bias_kernel<<<(M * NOUT) / (256 * 8), 256, 0, stream>>>(part, bias, coef, out);
}

// Round 6
// 36.870 us; speedup vs baseline: 1.5619x; 1.5619x over previous
//
#include <hip/hip_runtime.h>
#include <hip/hip_bf16.h>

#define M 256
#define NOUT 1024
#define KTOT 16384
#define RANK 16
#define NKC 32          // split-K factor
#define KCHUNK 512      // K per block = KTOT/NKC
#define BK 32           // K per LDS stage
#define NIT 16          // KCHUNK/BK
#define BN 64           // cols per block

typedef __attribute__((ext_vector_type(8))) short bf16x8_t;
typedef __attribute__((ext_vector_type(4))) float f32x4_t;
typedef __attribute__((ext_vector_type(8))) unsigned short u16x8_t;

static __device__ __forceinline__ unsigned short f2bf(float f) {
  unsigned u = __builtin_bit_cast(unsigned, f);
  u += 0x7FFFu + ((u >> 16) & 1u);   // round-to-nearest-even
  return (unsigned short)(u >> 16);
}
static __device__ __forceinline__ float bf2f(unsigned short h) {
  unsigned u = ((unsigned)h) << 16;
  return __builtin_bit_cast(float, u);
}

// X stored in 32-k chunks, source-side swizzled (rule #21):
//   element (b, k): chunk = k>>5, u = (k&31)>>3, el = k&7
//   pos = (chunk*256 + b)*32 + ((u ^ ((b>>1)&3)) * 8) + el     (bf16)
// A linear global_load_lds of a chunk gives 64 B LDS rows whose 16 B slots
// are permuted so fragment ds_read_b128 (slot = lg ^ ((row>>1)&3)) is 2-way
// bank-aliased only (free).
__global__ __launch_bounds__(256) void build_x_kernel(
    const float* __restrict__ input, const float* __restrict__ coef,
    unsigned short* __restrict__ X)
{
  int idx = blockIdx.x * 256 + threadIdx.x;   // idx = b*1024 + i
  int b = idx >> 10, i = idx & 1023;
  float in = input[idx];
  const float* c = coef + b * RANK;
  u16x8_t lo, hi;                              // k = i*16 + r
  #pragma unroll
  for (int r = 0; r < 8; ++r) lo[r] = f2bf(in * c[r]);
  #pragma unroll
  for (int r = 0; r < 8; ++r) hi[r] = f2bf(in * c[8 + r]);
  int chunk = i >> 1;            // (i*16)>>5
  int u0 = (i & 1) * 2;          // r<8 -> u0, r>=8 -> u0+1
  int sw = (b >> 1) & 3;
  size_t base = ((size_t)chunk * 256 + b) * 32;
  *(u16x8_t*)(X + base + (size_t)((u0    ) ^ sw) * 8) = lo;
  *(u16x8_t*)(X + base + (size_t)((u0 | 1) ^ sw) * 8) = hi;
}

// GEMM: part[kc][b][o] (bf16) = sum_{k in chunk kc} X[b][k] * W[o][k]
// Block: BM=256 (all M) x BN=64, BK=32, 512 threads (8 waves: 4 wr x 2 wc),
// wave tile 64 rows x 32 cols (fm=4, fn=2). W staged fp32 -> LDS exactly
// once grid-wide via global_load_lds (source-address swizzled per lane);
// all waves share it from LDS, cvt fp32->bf16 on fragment read. X staged
// from the pre-swizzled workspace. Plain double-buffered __syncthreads
// loop (m97 pattern); latency hidden by 16 waves/CU.
__global__ __launch_bounds__(512, 4) void gemm_kernel(
    const unsigned short* __restrict__ X, const float* __restrict__ W,
    unsigned short* __restrict__ part)
{
  __shared__ unsigned short As0[256 * 32];   // 16 KB
  __shared__ unsigned short As1[256 * 32];   // 16 KB
  __shared__ float          Bs0[64 * 32];    //  8 KB
  __shared__ float          Bs1[64 * 32];    //  8 KB

  const int tid = threadIdx.x;               // 0..511
  const int wid = tid >> 6, lane = tid & 63;
  const int lr = lane & 15, lg = lane >> 4;
  const int wr = wid >> 1, wc = wid & 1;     // 4x2 wave grid

  // chunked XCD swizzle (512 = 8*64, bijective): each XCD gets 4 complete
  // kc groups -> x-tile X-chunk sharing stays within one XCD's L2.
  const int lin = blockIdx.y * 16 + blockIdx.x;
  const int swb = (lin & 7) * 64 + (lin >> 3);
  const int xt = swb & 15, kc = swb >> 4;

  const int o0 = xt * BN;
  const int kb0 = kc * KCHUNK;
  const int c32_0 = kc * NIT;                // first 32-k chunk index

  f32x4_t acc[4][2];
  #pragma unroll
  for (int a = 0; a < 4; ++a) {
    acc[a][0] = (f32x4_t)(0.0f);
    acc[a][1] = (f32x4_t)(0.0f);
  }

  // B stage coords: thread t -> row t>>3 (0..63), slot u = t&7 of a 128 B
  // row; source slot u ^ (row&7)  -> LDS slot u holds source (u ^ (row&7)).
  const int brow = tid >> 3, bu = tid & 7;
  const float* bsrc = W + (size_t)(o0 + brow) * KTOT + ((bu ^ (brow & 7)) * 4);

  #define STAGE(it, ABUF, BBUF)                                              \
    {                                                                        \
      const unsigned short* srcb =                                           \
          X + (size_t)(c32_0 + (it)) * (256 * 32);                           \
      _Pragma("unroll")                                                      \
      for (int j = 0; j < 2; ++j) {                                          \
        int u = j * 512 + tid;                                               \
        __builtin_amdgcn_global_load_lds(                                    \
            (const __attribute__((address_space(1))) unsigned int*)          \
                (srcb + (size_t)u * 8),                                      \
            (__attribute__((address_space(3))) unsigned int*)                \
                (&ABUF[u * 8]),                                              \
            16, 0, 0);                                                       \
      }                                                                      \
      __builtin_amdgcn_global_load_lds(                                      \
          (const __attribute__((address_space(1))) unsigned int*)            \
              (bsrc + kb0 + (it) * BK),                                      \
          (__attribute__((address_space(3))) unsigned int*)                  \
              (&BBUF[tid * 4]),                                              \
          16, 0, 0);                                                         \
    }

  #define COMPUTE(ABUF, BBUF)                                                \
    {                                                                        \
      /* B frags: fn 0..1, row r = wc*32+fn*16+lr, floats [lg*8, lg*8+8) */  \
      /* stored at slots (2lg)^x,(2lg|1)^x with x=r&7 */                     \
      bf16x8_t bq0, bq1;                                                     \
      {                                                                      \
        int r0 = wc * 32 + lr,      x0 = r0 & 7;                             \
        int r1 = wc * 32 + 16 + lr, x1 = r1 & 7;                             \
        f32x4_t a0 = *(const f32x4_t*)&BBUF[r0 * 32 + (((2*lg)   ^ x0) * 4)];\
        f32x4_t a1 = *(const f32x4_t*)&BBUF[r0 * 32 + (((2*lg+1) ^ x0) * 4)];\
        f32x4_t c0 = *(const f32x4_t*)&BBUF[r1 * 32 + (((2*lg)   ^ x1) * 4)];\
        f32x4_t c1 = *(const f32x4_t*)&BBUF[r1 * 32 + (((2*lg+1) ^ x1) * 4)];\
        _Pragma("unroll")                                                    \
        for (int e = 0; e < 4; ++e) {                                        \
          bq0[e] = (short)f2bf(a0[e]); bq0[e + 4] = (short)f2bf(a1[e]);      \
          bq1[e] = (short)f2bf(c0[e]); bq1[e + 4] = (short)f2bf(c1[e]);      \
        }                                                                    \
      }                                                                      \
      _Pragma("unroll")                                                      \
      for (int fm = 0; fm < 4; ++fm) {                                       \
        int rl = wr * 64 + fm * 16 + lr;                                     \
        int slot = lg ^ ((rl >> 1) & 3);                                     \
        bf16x8_t av = *(const bf16x8_t*)&ABUF[rl * 32 + slot * 8];           \
        acc[fm][0] = __builtin_amdgcn_mfma_f32_16x16x32_bf16(                \
            av, bq0, acc[fm][0], 0, 0, 0);                                   \
        acc[fm][1] = __builtin_amdgcn_mfma_f32_16x16x32_bf16(                \
            av, bq1, acc[fm][1], 0, 0, 0);                                   \
      }                                                                      \
    }

  // ---- prologue ----
  STAGE(0, As0, Bs0)
  __syncthreads();

  // ---- main loop: stage next, compute current, one barrier per iter ----
  #pragma unroll
  for (int it = 0; it < NIT; ++it) {
    if (it + 1 < NIT) {
      if ((it + 1) & 1) { STAGE(it + 1, As1, Bs1) }
      else              { STAGE(it + 1, As0, Bs0) }
    }
    if (it & 1) { COMPUTE(As1, Bs1) }
    else        { COMPUTE(As0, Bs0) }
    __syncthreads();
  }

  // ---- epilogue: C/D layout col=lane&15, row=(lane>>4)*4+j ----
  unsigned short* p = part + (size_t)kc * (M * NOUT);
  #pragma unroll
  for (int fm = 0; fm < 4; ++fm) {
    #pragma unroll
    for (int fn = 0; fn < 2; ++fn) {
      #pragma unroll
      for (int j = 0; j < 4; ++j) {
        int row = wr * 64 + fm * 16 + lg * 4 + j;
        int col = o0 + wc * 32 + fn * 16 + lr;
        p[(size_t)row * NOUT + col] = f2bf(acc[fm][fn][j]);
      }
    }
  }
  #undef STAGE
  #undef COMPUTE
}

// out[b][o] = sum_kc bf2f(part[kc][b][o]) + sum_r bias[o][r]*coef[b][r]
__global__ __launch_bounds__(256) void reduce_bias_kernel(
    const unsigned short* __restrict__ part, const float* __restrict__ bias,
    const float* __restrict__ coef, float* __restrict__ out)
{
  int t = blockIdx.x * 256 + threadIdx.x;
  int idx8 = t * 8;                       // 8 consecutive outputs, same b
  int b = idx8 >> 10, o = idx8 & 1023;

  float s[8];
  #pragma unroll
  for (int j = 0; j < 8; ++j) s[j] = 0.f;

  #pragma unroll
  for (int c = 0; c < NKC; ++c) {
    u16x8_t v = *(const u16x8_t*)(part + (size_t)c * (M * NOUT) + idx8);
    #pragma unroll
    for (int j = 0; j < 8; ++j) s[j] += bf2f(v[j]);
  }

  const f32x4_t* cr = (const f32x4_t*)(coef + (size_t)b * RANK);
  f32x4_t c0 = cr[0], c1 = cr[1], c2 = cr[2], c3 = cr[3];
  #pragma unroll
  for (int j = 0; j < 8; ++j) {
    const f32x4_t* br = (const f32x4_t*)(bias + (size_t)(o + j) * RANK);
    f32x4_t b0 = br[0], b1 = br[1], b2 = br[2], b3 = br[3];
    float bb = 0.f;
    #pragma unroll
    for (int e = 0; e < 4; ++e)
      bb += b0[e] * c0[e] + b1[e] * c1[e] + b2[e] * c2[e] + b3[e] * c3[e];
    s[j] += bb;
  }
  float4* dst = (float4*)(out + idx8);
  dst[0] = make_float4(s[0], s[1], s[2], s[3]);
  dst[1] = make_float4(s[4], s[5], s[6], s[7]);
}

extern "C" void kernel_launch(void* const* d_in, const int* in_sizes, int n_in,
                              void* d_out, int out_size, void* d_ws, size_t ws_size,
                              hipStream_t stream) {
  const float* input = (const float*)d_in[0];   // (256, 1024)
  const float* coef  = (const float*)d_in[1];   // (256, 16)
  const float* W     = (const float*)d_in[2];   // (1024, 1024, 16) -> (1024, 16384)
  const float* bias  = (const float*)d_in[3];   // (1024, 16)
  float* out = (float*)d_out;                   // (256, 1024)

  unsigned short* X    = (unsigned short*)d_ws;                               // 8 MiB bf16
  unsigned short* part = (unsigned short*)((char*)d_ws + (size_t)M * KTOT * 2); // 16 MiB bf16

  build_x_kernel<<<(M * 1024) / 256, 256, 0, stream>>>(input, coef, X);
  gemm_kernel<<<dim3(NOUT / BN, NKC), 512, 0, stream>>>(X, W, part);
  reduce_bias_kernel<<<(M * NOUT) / (256 * 8), 256, 0, stream>>>(part, bias, coef, out);
}